// Round 1
// 242.214 us; speedup vs baseline: 1.0330x; 1.0330x over previous
//
#include <hip/hip_runtime.h>
#include <hip/hip_bf16.h>
#include <cstdint>
#include <cstddef>

typedef unsigned short u16;
typedef unsigned int u32;
typedef __attribute__((ext_vector_type(8))) short bf16x8;   // 8 bf16 = 4 VGPR
typedef __attribute__((ext_vector_type(4))) float f32x4;    // 16x16 MFMA C/D
typedef __attribute__((ext_vector_type(16))) float f32x16;  // 32x32 MFMA C/D
typedef __attribute__((ext_vector_type(4))) unsigned int u32x4;
typedef __attribute__((ext_vector_type(4))) unsigned short u16x4;

#define MFMA16(A,B,C) __builtin_amdgcn_mfma_f32_16x16x32_bf16(A,B,C,0,0,0)
#define MFMA32(A,B,C) __builtin_amdgcn_mfma_f32_32x32x16_bf16(A,B,C,0,0,0)

__device__ __forceinline__ u16 f2bf(float x) {
  __hip_bfloat16 h = __float2bfloat16(x);
  return __builtin_bit_cast(u16, h);
}

// raw v_exp_f32: single trans-pipe instruction (libm exp2f w/o fast-math takes
// the guarded __ocml path). Inputs here are <= ~11.6; deep negatives flush to 0,
// which is exactly the softmax tail behavior we want.
__device__ __forceinline__ float fast_exp2(float x) {
  float r;
  asm("v_exp_f32 %0, %1" : "=v"(r) : "v"(x));
  return r;
}

// v_permlane32_swap_b32 a, b:
//   a' = (a.lanes[0:31],  b.lanes[0:31])   [a.hi <- b.lo]
//   b' = (a.lanes[32:63], b.lanes[32:63])  [b.lo <- a.hi]
// i.e. after the op, a holds both lo-halves, b holds both hi-halves.
// One VALU instr replaces ds_bpermute + cndmask network (T12/m255: 1.2x).
__device__ __forceinline__ void permswap(u32& a, u32& b) {
  asm("v_permlane32_swap_b32 %0, %1" : "+v"(a), "+v"(b));
}

__device__ __forceinline__ void async_copy16(u16* lds, const u16* g) {
  __builtin_amdgcn_global_load_lds(
      (const __attribute__((address_space(1))) void*)g,
      (__attribute__((address_space(3))) void*)lds, 16, 0, 0);
}

// ------------------------------------------- fp32 -> bf16, up to 4 arrays/launch
__global__ void cvt4_kernel(const float* __restrict__ i0, const float* __restrict__ i1,
                            const float* __restrict__ i2, const float* __restrict__ i3,
                            u16* __restrict__ o0, u16* __restrict__ o1,
                            u16* __restrict__ o2, u16* __restrict__ o3, int n4) {
  const float* in; u16* out;
  switch (blockIdx.y) {
    case 0:  in = i0; out = o0; break;
    case 1:  in = i1; out = o1; break;
    case 2:  in = i2; out = o2; break;
    default: in = i3; out = o3; break;
  }
  int i = blockIdx.x * blockDim.x + threadIdx.x;
  int stride = gridDim.x * blockDim.x;
  for (; i < n4; i += stride) {
    float4 v = reinterpret_cast<const float4*>(in)[i];
    u16x4 o;
    o.x = f2bf(v.x); o.y = f2bf(v.y); o.z = f2bf(v.z); o.w = f2bf(v.w);
    reinterpret_cast<u16x4*>(out)[i] = o;
  }
}

// ------------------------------------------------- GEMM NT: C = (A*W^T + bias)*scale
// Grid is (m-tiles, n-tiles): linear wg id % 8 = mtile % 8, so the 8 blocks that
// share an A-panel (same m0, all n0) land on ONE XCD -> A read once from HBM/L3
// instead of 8x through every XCD's L2.
template<bool BF16OUT>
__global__ __launch_bounds__(256, 2)
void gemm_nt_bias(const u16* __restrict__ A, const u16* __restrict__ W,
                  const float* __restrict__ bias, void* __restrict__ Cout,
                  int M, int N, int K, float scale) {
  __shared__ __attribute__((aligned(16))) u16 As[128*32];
  __shared__ __attribute__((aligned(16))) u16 Bs[128*32];
  const int t = threadIdx.x;
  const int lane = t & 63, wid = t >> 6;
  const int wr = wid >> 1, wc = wid & 1;
  const int g = lane >> 4, qc = lane & 15;
  const size_t m0 = (size_t)blockIdx.x * 128;
  const size_t n0 = (size_t)blockIdx.y * 128;
  f32x4 acc[4][4] = {};

  for (int k0 = 0; k0 < K; k0 += 32) {
    __syncthreads();
    #pragma unroll
    for (int c = 0; c < 2; ++c) {
      int s = c*256 + t;
      int row = s >> 2, ch = s & 3;
      int sch = ch ^ ((row >> 1) & 3);
      async_copy16(&As[s*8], &A[(m0 + row)*K + k0 + sch*8]);
    }
    #pragma unroll
    for (int c = 0; c < 2; ++c) {
      int s = c*256 + t;
      int row = s >> 2, ch = s & 3;
      int sch = ch ^ ((row >> 1) & 3);
      async_copy16(&Bs[s*8], &W[(n0 + row)*K + k0 + sch*8]);
    }
    __syncthreads();
    bf16x8 af[4], bfr[4];
    #pragma unroll
    for (int i = 0; i < 4; ++i) {
      int r = wr*64 + i*16 + qc;
      int ch = g ^ ((r >> 1) & 3);
      af[i] = *reinterpret_cast<const bf16x8*>(&As[r*32 + ch*8]);
    }
    #pragma unroll
    for (int j = 0; j < 4; ++j) {
      int r = wc*64 + j*16 + qc;
      int ch = g ^ ((r >> 1) & 3);
      bfr[j] = *reinterpret_cast<const bf16x8*>(&Bs[r*32 + ch*8]);
    }
    #pragma unroll
    for (int i = 0; i < 4; ++i)
      #pragma unroll
      for (int j = 0; j < 4; ++j)
        acc[i][j] = MFMA16(af[i], bfr[j], acc[i][j]);
  }

  #pragma unroll
  for (int j = 0; j < 4; ++j) {
    size_t col = n0 + wc*64 + j*16 + qc;
    float bv = bias[col];
    #pragma unroll
    for (int i = 0; i < 4; ++i) {
      #pragma unroll
      for (int r = 0; r < 4; ++r) {
        size_t row = m0 + wr*64 + i*16 + g*4 + r;
        float v = (acc[i][j][r] + bv) * scale;
        if (BF16OUT) ((u16*)Cout)[row*N + col] = f2bf(v);
        else         ((float*)Cout)[row*N + col] = v;
      }
    }
  }
}

// --------------------------------------------------------------- flash attention v13
// v12 + (a) permlane32_swap replaces the bpermute/cndmask half-exchange in the PV
// recombination and the cross-half softmax reduces, (b) s_setprio(1) around MFMA
// clusters, (c) grid dims swapped so same-(b,h) blocks share an XCD (K/V L2 reuse).
__global__ __launch_bounds__(512, 4)
void flash_attn3(const u16* __restrict__ Qp, const u16* __restrict__ Kp,
                 const u16* __restrict__ Vp, u16* __restrict__ O) {
  __shared__ __attribute__((aligned(16))) u16 Ks[2][64*64];
  __shared__ __attribute__((aligned(16))) u16 Vt[3][64*64];
  const int t = threadIdx.x;
  const int w = t >> 6, lane = t & 63;
  const int l31 = lane & 31, hi = lane >> 5;
  const int bh = blockIdx.x;                    // swapped: bh fastest -> id%8 = bh%8
  const size_t rowbase = (size_t)(bh >> 4) * 2048;
  const int hoff = (bh & 15) * 64;
  const int q0 = blockIdx.y * 256 + w * 32;
  const float THR = 11.5415603f;   // 8 * log2(e)

  // Q B-frags (Q pre-scaled by 0.125*log2(e) in projection epilogue)
  bf16x8 bq[4];
  {
    const u16* qp = &Qp[(rowbase + q0 + l31) * 1024 + hoff + hi * 8];
    #pragma unroll
    for (int dd = 0; dd < 4; ++dd) bq[dd] = *reinterpret_cast<const bf16x8*>(qp + dd*16);
  }

  f32x16 accO[2] = {};
  float m_run = 0.f, l_run = 0.f;   // log2 domain; scores tracked relative to m_run
  u32 pwp[2][8];                    // packed P(t-1)

  const int kvr_s = t >> 3, c_s = t & 7;
  const int sc_s = c_s ^ ((kvr_s >> 3) & 7);      // pre-swizzled K source chunk
  const int vd0_s = (t & 7) * 8;
  const int vcs = kvr_s >> 3;

  // prologue: tile 0
  async_copy16(&Ks[0][t*8], &Kp[(rowbase + kvr_s)*1024 + hoff + sc_s*8]);
  bf16x8 vreg = *reinterpret_cast<const bf16x8*>(&Vp[(rowbase + kvr_s)*1024 + hoff + vd0_s]);

  int wi = 0, ri = 2;   // V write = kv%3, V read (tile kv-1) = (kv+2)%3
  for (int kv = 0; kv < 32; ++kv) {
    const int kb = kv & 1;
    u16* vw = &Vt[0][0] + wi*4096;
    const u16* vrd = &Vt[0][0] + ri*4096;

    // V(kv) regs -> LDS, transposed + chunk-swizzled
    #pragma unroll
    for (int j = 0; j < 8; ++j) {
      int d = vd0_s + j;
      vw[d*64 + ((vcs ^ ((d>>3)&7))*8) + (kvr_s & 7)] = (u16)vreg[j];
    }
    __syncthreads();
    if (kv < 31) {
      const size_t nb = rowbase + (size_t)(kv+1)*64;
      async_copy16(&Ks[kb^1][t*8], &Kp[(nb + kvr_s)*1024 + hoff + sc_s*8]);
      vreg = *reinterpret_cast<const bf16x8*>(&Vp[(nb + kvr_s)*1024 + hoff + vd0_s]);
    }

    // ---- QK^T(kv), swapped; C initialized to -m_run so sacc = S - m_old
    f32x16 sacc[2];
    {
      const float negm = -m_run;
      #pragma unroll
      for (int i = 0; i < 16; ++i) { sacc[0][i] = negm; sacc[1][i] = negm; }
    }
    __builtin_amdgcn_s_setprio(1);
    #pragma unroll
    for (int n = 0; n < 2; ++n) {
      int kvr = n*32 + l31;
      int swz = (kvr >> 3) & 7;
      #pragma unroll
      for (int dd = 0; dd < 4; ++dd) {
        int ch = (2*dd + hi) ^ swz;
        bf16x8 ak = *reinterpret_cast<const bf16x8*>(&Ks[kb][kvr*64 + ch*8]);
        sacc[n] = MFMA32(ak, bq[dd], sacc[n]);
      }
    }
    __builtin_amdgcn_s_setprio(0);

    // ---- deferred PV(kv-1): overlaps softmax VALU below (independent regs)
    if (kv > 0) {
      __builtin_amdgcn_s_setprio(1);
      #pragma unroll
      for (int ks = 0; ks < 4; ++ks) {
        const int n = ks >> 1, kp = ks & 1;
        u32 wA0 = pwp[n][4*kp+0], wA1 = pwp[n][4*kp+1];
        u32 wB0 = pwp[n][4*kp+2], wB1 = pwp[n][4*kp+3];
        permswap(wA0, wB0);   // wA0 = fu.x (both lo-halves), wB0 = fu.z (both hi)
        permswap(wA1, wB1);   // wA1 = fu.y,                  wB1 = fu.w
        u32x4 fu;
        fu.x = wA0; fu.y = wA1; fu.z = wB0; fu.w = wB1;
        bf16x8 pa = __builtin_bit_cast(bf16x8, fu);
        #pragma unroll
        for (int dt = 0; dt < 2; ++dt) {
          int d = dt*32 + l31;
          int ch = (2*ks + hi) ^ ((d>>3)&7);
          bf16x8 bv = *reinterpret_cast<const bf16x8*>(&vrd[d*64 + ch*8]);
          accO[dt] = MFMA32(pa, bv, accO[dt]);
        }
      }
      __builtin_amdgcn_s_setprio(0);
    }

    // ---- softmax(kv): 3-ary max nest (v_max3-fusable)
    float a0 = fmaxf(fmaxf(sacc[0][0],sacc[0][1]),sacc[0][2]);
    float a1 = fmaxf(fmaxf(sacc[0][3],sacc[0][4]),sacc[0][5]);
    float a2 = fmaxf(fmaxf(sacc[0][6],sacc[0][7]),sacc[0][8]);
    float a3 = fmaxf(fmaxf(sacc[0][9],sacc[0][10]),sacc[0][11]);
    float a4 = fmaxf(fmaxf(sacc[0][12],sacc[0][13]),sacc[0][14]);
    float a5 = fmaxf(fmaxf(sacc[0][15],sacc[1][0]),sacc[1][1]);
    float a6 = fmaxf(fmaxf(sacc[1][2],sacc[1][3]),sacc[1][4]);
    float a7 = fmaxf(fmaxf(sacc[1][5],sacc[1][6]),sacc[1][7]);
    float a8 = fmaxf(fmaxf(sacc[1][8],sacc[1][9]),sacc[1][10]);
    float a9 = fmaxf(fmaxf(sacc[1][11],sacc[1][12]),sacc[1][13]);
    float aA = fmaxf(sacc[1][14],sacc[1][15]);
    float b0 = fmaxf(fmaxf(a0,a1),a2);
    float b1 = fmaxf(fmaxf(a3,a4),a5);
    float b2 = fmaxf(fmaxf(a6,a7),a8);
    float b3 = fmaxf(a9,aA);
    float mloc = fmaxf(fmaxf(b0,b1),fmaxf(b2,b3));
    // cross-half max via permlane32_swap (no ds_bpermute on the critical path)
    float mx;
    {
      u32 ma = __builtin_bit_cast(u32, mloc), mb = ma;
      permswap(ma, mb);                 // ma = (lo,lo), mb = (hi,hi)
      float other = __builtin_bit_cast(float, hi ? ma : mb);
      mx = fmaxf(mloc, other);          // relative to m_run
    }

    if (__any(mx > THR)) {   // rare: max grew beyond the defer threshold
      float dm = fmaxf(mx, 0.f);
      float alpha = fast_exp2(-dm);
      m_run += dm;
      l_run *= alpha;
      #pragma unroll
      for (int n = 0; n < 2; ++n)
        #pragma unroll
        for (int r = 0; r < 16; ++r) sacc[n][r] -= dm;
      #pragma unroll
      for (int r = 0; r < 16; ++r) {
        int qrow = (r&3) + 8*(r>>2) + 4*hi;
        float ar = __shfl(alpha, qrow);
        accO[0][r] *= ar; accO[1][r] *= ar;
      }
    }

    // ---- exp2 in place (raw v_exp_f32), RNE f2bf pack, sum tree
    #pragma unroll
    for (int n = 0; n < 2; ++n)
      #pragma unroll
      for (int r = 0; r < 16; ++r) sacc[n][r] = fast_exp2(sacc[n][r]);
    #pragma unroll
    for (int n = 0; n < 2; ++n)
      #pragma unroll
      for (int i = 0; i < 8; ++i)
        pwp[n][i] = (u32)f2bf(sacc[n][2*i]) | ((u32)f2bf(sacc[n][2*i+1]) << 16);
    float ts[16];
    #pragma unroll
    for (int i = 0; i < 16; ++i) ts[i] = sacc[0][i] + sacc[1][i];
    #pragma unroll
    for (int off = 8; off >= 1; off >>= 1)
      #pragma unroll
      for (int i = 0; i < off; ++i) ts[i] += ts[i + off];
    {
      u32 sa = __builtin_bit_cast(u32, ts[0]), sb = sa;
      permswap(sa, sb);                 // sa = (lo,lo), sb = (hi,hi)
      float other = __builtin_bit_cast(float, hi ? sa : sb);
      l_run += ts[0] + other;
    }

    wi = (wi == 2) ? 0 : wi + 1;
    ri = (ri == 2) ? 0 : ri + 1;
  }

  // ---- epilogue PV(31)
  {
    const u16* vrd = &Vt[0][0] + ri*4096;
    __builtin_amdgcn_s_setprio(1);
    #pragma unroll
    for (int ks = 0; ks < 4; ++ks) {
      const int n = ks >> 1, kp = ks & 1;
      u32 wA0 = pwp[n][4*kp+0], wA1 = pwp[n][4*kp+1];
      u32 wB0 = pwp[n][4*kp+2], wB1 = pwp[n][4*kp+3];
      permswap(wA0, wB0);
      permswap(wA1, wB1);
      u32x4 fu;
      fu.x = wA0; fu.y = wA1; fu.z = wB0; fu.w = wB1;
      bf16x8 pa = __builtin_bit_cast(bf16x8, fu);
      #pragma unroll
      for (int dt = 0; dt < 2; ++dt) {
        int d = dt*32 + l31;
        int ch = (2*ks + hi) ^ ((d>>3)&7);
        bf16x8 bv = *reinterpret_cast<const bf16x8*>(&vrd[d*64 + ch*8]);
        accO[dt] = MFMA32(pa, bv, accO[dt]);
      }
    }
    __builtin_amdgcn_s_setprio(0);
  }

  // ---- epilogue: O[q'][d] * (1/l[q']), l for row q' pulled from lane q'
  float linv = 1.0f / l_run;
  #pragma unroll
  for (int r = 0; r < 16; ++r) {
    int qrow = (r&3) + 8*(r>>2) + 4*hi;
    float lv = __shfl(linv, qrow);
    size_t orow = rowbase + q0 + qrow;
    O[orow*1024 + hoff + l31]      = f2bf(accO[0][r] * lv);
    O[orow*1024 + hoff + 32 + l31] = f2bf(accO[1][r] * lv);
  }
}

// ------------------------------------------------------------------------------
extern "C" void kernel_launch(void* const* d_in, const int* in_sizes, int n_in,
                              void* d_out, int out_size, void* d_ws, size_t ws_size,
                              hipStream_t stream) {
  (void)in_sizes; (void)n_in; (void)out_size; (void)ws_size;
  const float* query = (const float*)d_in[0];
  const float* key   = (const float*)d_in[1];
  const float* value = (const float*)d_in[2];
  const float* W_q   = (const float*)d_in[3];
  const float* b_q   = (const float*)d_in[4];
  const float* W_k   = (const float*)d_in[5];
  const float* b_k   = (const float*)d_in[6];
  const float* W_v   = (const float*)d_in[7];
  const float* b_v   = (const float*)d_in[8];
  const float* W_o   = (const float*)d_in[9];
  const float* b_o   = (const float*)d_in[10];

  const size_t sz_t = (size_t)8192 * 1024;
  const size_t sz_w = (size_t)1024 * 1024;
  u16* ws = (u16*)d_ws;
  u16* xq = ws;                 // also attn-output staging after Q-GEMM consumes it
  u16* xk = ws + 1*sz_t;
  u16* xv = ws + 2*sz_t;
  u16* Qp = ws + 3*sz_t;
  u16* Kp = ws + 4*sz_t;
  u16* Vp = ws + 5*sz_t;
  u16* wq = ws + 6*sz_t;
  u16* wk = wq + sz_w;
  u16* wv = wq + 2*sz_w;
  u16* wo = wq + 3*sz_w;

  const float SCL = 0.125f * 1.44269504089f;  // softmax scale, folded into Q proj

  cvt4_kernel<<<dim3(512, 4), 256, 0, stream>>>(W_q, W_k, W_v, W_o,
                                                wq, wk, wv, wo, (int)(sz_w/4));
  cvt4_kernel<<<dim3(2048, 3), 256, 0, stream>>>(query, key, value, value,
                                                 xq, xk, xv, xv, (int)(sz_t/4));

  // grid = (m-tiles, n-tiles): A-panel sharers co-locate per XCD
  dim3 gg(8192/128, 1024/128);
  gemm_nt_bias<true><<<gg, 256, 0, stream>>>(xq, wq, b_q, Qp, 8192, 1024, 1024, SCL);
  gemm_nt_bias<true><<<gg, 256, 0, stream>>>(xk, wk, b_k, Kp, 8192, 1024, 1024, 1.0f);
  gemm_nt_bias<true><<<gg, 256, 0, stream>>>(xv, wv, b_v, Vp, 8192, 1024, 1024, 1.0f);

  // grid = (bh, q-tiles): K/V-panel sharers co-locate per XCD
  flash_attn3<<<dim3(64, 8), 512, 0, stream>>>(Qp, Kp, Vp, xq);

  gemm_nt_bias<false><<<gg, 256, 0, stream>>>(xq, wo, b_o, d_out, 8192, 1024, 1024, 1.0f);
}